// Round 1
// baseline (21106.790 us; speedup 1.0000x reference)
//
#include <hip/hip_runtime.h>

// ESN recurrence on MI355X: h_t = tanh(x_t @ W_in^T + h_{t-1} @ W_res^T)
// B=64, T=512, I=128, H=2048. Persistent cooperative kernel, 256 WGs (1/CU).
// WG (bg,j): batches [bg*16, bg*16+16), rows [j*32, j*32+32).
// W_res slice fp16 in LDS (resident all 512 steps); W_in slice fp16 hi+lo in LDS.
// Per step: fp16 MFMA 16x16x32 accumulating fp32; x@W_in^T done with hi/lo split
// (3 MFMA groups) for precision; h broadcast through global as fp16, double-buffered,
// custom device-scope barrier per step (release atomicAdd + per-wave acquire spin).

#define B_ 64
#define T_ 512
#define I_ 128
#define H_ 2048
#define NWG 256
#define ROWS 32          // output rows per WG
#define BATS 16          // batches per WG
#define WPAD 2056        // 2048 + 8 halves row pad (LDS bank decorrelation)
#define IPAD 136         // 128 + 8 halves row pad
#define PPAD 33          // partial row pad (break 32-bank stride)

typedef _Float16 f16;
typedef f16 f16x8 __attribute__((ext_vector_type(8)));
typedef float f32x4 __attribute__((ext_vector_type(4)));

// LDS layout (bytes):
//   Wres  : ROWS*WPAD*2           = 131584
//   Win_hi: ROWS*IPAD*2           =   8704
//   Win_lo: ROWS*IPAD*2           =   8704
//   part  : 4*BATS*PPAD*4         =   8448
#define LDS_WRES   0
#define LDS_WINHI  131584
#define LDS_WINLO  (131584 + 8704)
#define LDS_PART   (131584 + 17408)
#define LDS_TOTAL  (131584 + 17408 + 8448)

extern "C" __global__ __launch_bounds__(256, 1)
void esn_kernel(const float* __restrict__ x, const float* __restrict__ Win,
                const float* __restrict__ Wres, float* __restrict__ out,
                f16* h0, f16* h1, int* cnt)
{
    extern __shared__ char lds[];
    f16*   Wr   = (f16*)(lds + LDS_WRES);    // [ROWS][WPAD]
    f16*   Whi  = (f16*)(lds + LDS_WINHI);   // [ROWS][IPAD]
    f16*   Wlo  = (f16*)(lds + LDS_WINLO);   // [ROWS][IPAD]
    float* part = (float*)(lds + LDS_PART);  // [4][BATS][PPAD]

    const int tid  = threadIdx.x;
    const int wg   = blockIdx.x;
    const int j    = wg & 63;       // row group
    const int bg   = wg >> 6;       // batch group
    const int r0   = j * ROWS;
    const int b0   = bg * BATS;
    const int wv   = tid >> 6;      // wave 0..3
    const int lane = tid & 63;
    const int lm   = lane & 15;     // A: m index / B: n index / C: col index
    const int quad = lane >> 4;     // 0..3

    // ---- one-time init: stage W_res slice (fp32 -> fp16) into LDS ----
    for (int idx = tid; idx < ROWS * (H_ / 4); idx += 256) {
        int r  = idx >> 9;          // 512 float4 per row
        int c4 = idx & 511;
        const float4 v = ((const float4*)(Wres + (size_t)(r0 + r) * H_))[c4];
        f16* dst = Wr + r * WPAD + c4 * 4;
        dst[0] = (f16)v.x; dst[1] = (f16)v.y; dst[2] = (f16)v.z; dst[3] = (f16)v.w;
    }
    // ---- W_in slice as fp16 hi + lo (precision split) ----
    for (int idx = tid; idx < ROWS * (I_ / 4); idx += 256) {
        int r  = idx >> 5;          // 32 float4 per row
        int c4 = idx & 31;
        const float4 v = ((const float4*)(Win + (size_t)(r0 + r) * I_))[c4];
        float vv[4] = {v.x, v.y, v.z, v.w};
        f16* dh = Whi + r * IPAD + c4 * 4;
        f16* dl = Wlo + r * IPAD + c4 * 4;
        #pragma unroll
        for (int q = 0; q < 4; q++) {
            f16 hi = (f16)vv[q];
            dh[q] = hi;
            dl[q] = (f16)(vv[q] - (float)hi);
        }
    }
    __syncthreads();

    for (int t = 0; t < T_; t++) {
        const f16* hprev = (t & 1) ? h1 : h0;
        f16*       hnext = (t & 1) ? h0 : h1;

        f32x4 acc0 = {0.f, 0.f, 0.f, 0.f};
        f32x4 acc1 = {0.f, 0.f, 0.f, 0.f};

        // ---- x_t @ W_in^T with fp16 hi/lo split; wave wv covers k in [wv*32, wv*32+32) ----
        {
            const int kin = wv * 32 + quad * 8;
            const float* xp = x + ((size_t)(b0 + lm) * T_ + t) * I_ + kin;
            float xf[8];
            *(float4*)(xf)     = *(const float4*)(xp);
            *(float4*)(xf + 4) = *(const float4*)(xp + 4);
            f16x8 xhi, xlo;
            #pragma unroll
            for (int q = 0; q < 8; q++) {
                f16 hi = (f16)xf[q];
                xhi[q] = hi;
                xlo[q] = (f16)(xf[q] - (float)hi);
            }
            f16x8 bh0 = *(const f16x8*)(Whi + lm * IPAD + kin);
            f16x8 bh1 = *(const f16x8*)(Whi + (lm + 16) * IPAD + kin);
            f16x8 bl0 = *(const f16x8*)(Wlo + lm * IPAD + kin);
            f16x8 bl1 = *(const f16x8*)(Wlo + (lm + 16) * IPAD + kin);
            acc0 = __builtin_amdgcn_mfma_f32_16x16x32_f16(xhi, bh0, acc0, 0, 0, 0);
            acc1 = __builtin_amdgcn_mfma_f32_16x16x32_f16(xhi, bh1, acc1, 0, 0, 0);
            acc0 = __builtin_amdgcn_mfma_f32_16x16x32_f16(xlo, bh0, acc0, 0, 0, 0);
            acc1 = __builtin_amdgcn_mfma_f32_16x16x32_f16(xlo, bh1, acc1, 0, 0, 0);
            acc0 = __builtin_amdgcn_mfma_f32_16x16x32_f16(xhi, bl0, acc0, 0, 0, 0);
            acc1 = __builtin_amdgcn_mfma_f32_16x16x32_f16(xhi, bl1, acc1, 0, 0, 0);
        }

        // ---- h_{t-1} @ W_res^T ; wave wv covers k in [wv*512, (wv+1)*512) ----
        {
            const f16* hp = hprev + (size_t)(b0 + lm) * H_ + wv * 512 + quad * 8;
            const f16* w0 = Wr + lm * WPAD + wv * 512 + quad * 8;
            const f16* w1 = Wr + (lm + 16) * WPAD + wv * 512 + quad * 8;
            #pragma unroll 4
            for (int ks = 0; ks < 16; ks++) {
                f16x8 a  = *(const f16x8*)(hp + ks * 32);   // global, 16B/lane
                f16x8 bf0 = *(const f16x8*)(w0 + ks * 32);  // LDS ds_read_b128
                f16x8 bf1 = *(const f16x8*)(w1 + ks * 32);
                acc0 = __builtin_amdgcn_mfma_f32_16x16x32_f16(a, bf0, acc0, 0, 0, 0);
                acc1 = __builtin_amdgcn_mfma_f32_16x16x32_f16(a, bf1, acc1, 0, 0, 0);
            }
        }

        // ---- per-wave partials to LDS (C/D layout: col=lane&15, row=quad*4+reg) ----
        {
            float* pw = part + wv * (BATS * PPAD);
            #pragma unroll
            for (int r = 0; r < 4; r++) {
                int m = quad * 4 + r;
                pw[m * PPAD + lm]      = acc0[r];
                pw[m * PPAD + 16 + lm] = acc1[r];
            }
        }
        __syncthreads();

        // ---- reduce 4 waves + tanh + store slice (512 outputs / 256 threads) ----
        for (int idx = tid; idx < BATS * ROWS; idx += 256) {
            int m = idx >> 5;
            int n = idx & 31;
            int o = m * PPAD + n;
            float s = part[o] + part[BATS * PPAD + o] + part[2 * BATS * PPAD + o]
                    + part[3 * BATS * PPAD + o];
            s = tanhf(s);
            if (t == T_ - 1) {
                out[(size_t)(b0 + m) * H_ + r0 + n] = s;       // final: fp32
            } else {
                hnext[(size_t)(b0 + m) * H_ + r0 + n] = (f16)s; // broadcast: fp16
            }
        }

        // ---- grid barrier (skip after last step) ----
        if (t < T_ - 1) {
            __syncthreads();  // all waves' h stores drained (vmcnt 0) before arrival
            if (tid == 0) {
                __hip_atomic_fetch_add(cnt, 1, __ATOMIC_RELEASE, __HIP_MEMORY_SCOPE_AGENT);
            }
            const int target = NWG * (t + 1);
            // every wave acquire-spins -> per-wave ordering for next step's h loads
            while (__hip_atomic_load(cnt, __ATOMIC_ACQUIRE, __HIP_MEMORY_SCOPE_AGENT) < target) {
                __builtin_amdgcn_s_sleep(1);
            }
        }
    }
}

extern "C" void kernel_launch(void* const* d_in, const int* in_sizes, int n_in,
                              void* d_out, int out_size, void* d_ws, size_t ws_size,
                              hipStream_t stream)
{
    (void)in_sizes; (void)n_in; (void)out_size; (void)ws_size;
    const float* x    = (const float*)d_in[0];
    const float* Win  = (const float*)d_in[1];
    const float* Wres = (const float*)d_in[2];
    float* out = (float*)d_out;

    f16* h0 = (f16*)d_ws;
    f16* h1 = h0 + (size_t)B_ * H_;
    int* cnt = (int*)((char*)d_ws + (size_t)2 * B_ * H_ * sizeof(f16));

    // zero h ping-pong buffers (h_0 = 0) and the barrier counter
    hipMemsetAsync(d_ws, 0, (size_t)2 * B_ * H_ * sizeof(f16) + 64, stream);

    hipFuncSetAttribute((const void*)esn_kernel,
                        hipFuncAttributeMaxDynamicSharedMemorySize, LDS_TOTAL);

    void* args[] = {(void*)&x, (void*)&Win, (void*)&Wres, (void*)&out,
                    (void*)&h0, (void*)&h1, (void*)&cnt};
    hipLaunchCooperativeKernel((const void*)esn_kernel, dim3(NWG), dim3(256),
                               args, LDS_TOTAL, stream);
}

// Round 2
// 12255.364 us; speedup vs baseline: 1.7222x; 1.7222x over previous
//
#include <hip/hip_runtime.h>

// ESN recurrence on MI355X: h_t = tanh(x_t @ W_in^T + h_{t-1} @ W_res^T)
// B=64, T=512, I=128, H=2048. Persistent cooperative kernel, 256 WGs (1/CU).
// WG (bg,j): batches [bg*16, bg*16+16), rows [j*32, j*32+32).
// W_res slice fp16 in LDS (resident all 512 steps); W_in slice fp16 hi+lo in LDS.
// R2: counter barrier -> bg-segmented flag barrier. Producers release-store a
// private flag (no RMW contention); only wave 0 polls, 64 flags in ONE vector
// load per poll; acquire fence once per step. h fragments prefetched to regs.

#define B_ 64
#define T_ 512
#define I_ 128
#define H_ 2048
#define NWG 256
#define ROWS 32          // output rows per WG
#define BATS 16          // batches per WG
#define WPAD 2056        // 2048 + 8 halves row pad (LDS bank decorrelation)
#define IPAD 136         // 128 + 8 halves row pad
#define PPAD 33          // partial row pad (break 32-bank stride)

typedef _Float16 f16;
typedef f16 f16x8 __attribute__((ext_vector_type(8)));
typedef float f32x4 __attribute__((ext_vector_type(4)));

// LDS layout (bytes):
//   Wres  : ROWS*WPAD*2           = 131584
//   Win_hi: ROWS*IPAD*2           =   8704
//   Win_lo: ROWS*IPAD*2           =   8704
//   part  : 4*BATS*PPAD*4         =   8448
#define LDS_WRES   0
#define LDS_WINHI  131584
#define LDS_WINLO  (131584 + 8704)
#define LDS_PART   (131584 + 17408)
#define LDS_TOTAL  (131584 + 17408 + 8448)

extern "C" __global__ __launch_bounds__(256, 1)
void esn_kernel(const float* __restrict__ x, const float* __restrict__ Win,
                const float* __restrict__ Wres, float* __restrict__ out,
                f16* h0, f16* h1, int* flags)
{
    extern __shared__ char lds[];
    f16*   Wr   = (f16*)(lds + LDS_WRES);    // [ROWS][WPAD]
    f16*   Whi  = (f16*)(lds + LDS_WINHI);   // [ROWS][IPAD]
    f16*   Wlo  = (f16*)(lds + LDS_WINLO);   // [ROWS][IPAD]
    float* part = (float*)(lds + LDS_PART);  // [4][BATS][PPAD]

    const int tid  = threadIdx.x;
    const int wg   = blockIdx.x;
    const int j    = wg & 63;       // row group
    const int bg   = wg >> 6;       // batch group
    const int r0   = j * ROWS;
    const int b0   = bg * BATS;
    const int wv   = tid >> 6;      // wave 0..3
    const int lane = tid & 63;
    const int lm   = lane & 15;     // A: m index / B: n index / C: col index
    const int quad = lane >> 4;     // 0..3

    // ---- one-time init: stage W_res slice (fp32 -> fp16) into LDS ----
    for (int idx = tid; idx < ROWS * (H_ / 4); idx += 256) {
        int r  = idx >> 9;          // 512 float4 per row
        int c4 = idx & 511;
        const float4 v = ((const float4*)(Wres + (size_t)(r0 + r) * H_))[c4];
        f16* dst = Wr + r * WPAD + c4 * 4;
        dst[0] = (f16)v.x; dst[1] = (f16)v.y; dst[2] = (f16)v.z; dst[3] = (f16)v.w;
    }
    // ---- W_in slice as fp16 hi + lo (precision split) ----
    for (int idx = tid; idx < ROWS * (I_ / 4); idx += 256) {
        int r  = idx >> 5;          // 32 float4 per row
        int c4 = idx & 31;
        const float4 v = ((const float4*)(Win + (size_t)(r0 + r) * I_))[c4];
        float vv[4] = {v.x, v.y, v.z, v.w};
        f16* dh = Whi + r * IPAD + c4 * 4;
        f16* dl = Wlo + r * IPAD + c4 * 4;
        #pragma unroll
        for (int q = 0; q < 4; q++) {
            f16 hi = (f16)vv[q];
            dh[q] = hi;
            dl[q] = (f16)(vv[q] - (float)hi);
        }
    }
    __syncthreads();

    for (int t = 0; t < T_; t++) {
        const f16* hprev = (t & 1) ? h1 : h0;
        f16*       hnext = (t & 1) ? h0 : h1;

        f32x4 acc0 = {0.f, 0.f, 0.f, 0.f};
        f32x4 acc1 = {0.f, 0.f, 0.f, 0.f};

        // ---- prefetch h fragments (16 x 16B/lane) to registers; covers IF latency ----
        f16x8 a[16];
        {
            const f16* hp = hprev + (size_t)(b0 + lm) * H_ + wv * 512 + quad * 8;
            #pragma unroll
            for (int ks = 0; ks < 16; ks++) a[ks] = *(const f16x8*)(hp + ks * 32);
        }

        // ---- x_t @ W_in^T with fp16 hi/lo split; wave wv covers k in [wv*32, wv*32+32) ----
        {
            const int kin = wv * 32 + quad * 8;
            const float* xp = x + ((size_t)(b0 + lm) * T_ + t) * I_ + kin;
            float xf[8];
            *(float4*)(xf)     = *(const float4*)(xp);
            *(float4*)(xf + 4) = *(const float4*)(xp + 4);
            f16x8 xhi, xlo;
            #pragma unroll
            for (int q = 0; q < 8; q++) {
                f16 hi = (f16)xf[q];
                xhi[q] = hi;
                xlo[q] = (f16)(xf[q] - (float)hi);
            }
            f16x8 bh0 = *(const f16x8*)(Whi + lm * IPAD + kin);
            f16x8 bh1 = *(const f16x8*)(Whi + (lm + 16) * IPAD + kin);
            f16x8 bl0 = *(const f16x8*)(Wlo + lm * IPAD + kin);
            f16x8 bl1 = *(const f16x8*)(Wlo + (lm + 16) * IPAD + kin);
            acc0 = __builtin_amdgcn_mfma_f32_16x16x32_f16(xhi, bh0, acc0, 0, 0, 0);
            acc1 = __builtin_amdgcn_mfma_f32_16x16x32_f16(xhi, bh1, acc1, 0, 0, 0);
            acc0 = __builtin_amdgcn_mfma_f32_16x16x32_f16(xlo, bh0, acc0, 0, 0, 0);
            acc1 = __builtin_amdgcn_mfma_f32_16x16x32_f16(xlo, bh1, acc1, 0, 0, 0);
            acc0 = __builtin_amdgcn_mfma_f32_16x16x32_f16(xhi, bl0, acc0, 0, 0, 0);
            acc1 = __builtin_amdgcn_mfma_f32_16x16x32_f16(xhi, bl1, acc1, 0, 0, 0);
        }

        // ---- h_{t-1} @ W_res^T ; wave wv covers k in [wv*512, (wv+1)*512) ----
        {
            const f16* w0 = Wr + lm * WPAD + wv * 512 + quad * 8;
            const f16* w1 = Wr + (lm + 16) * WPAD + wv * 512 + quad * 8;
            #pragma unroll
            for (int ks = 0; ks < 16; ks++) {
                f16x8 bf0 = *(const f16x8*)(w0 + ks * 32);  // LDS ds_read_b128
                f16x8 bf1 = *(const f16x8*)(w1 + ks * 32);
                acc0 = __builtin_amdgcn_mfma_f32_16x16x32_f16(a[ks], bf0, acc0, 0, 0, 0);
                acc1 = __builtin_amdgcn_mfma_f32_16x16x32_f16(a[ks], bf1, acc1, 0, 0, 0);
            }
        }

        // ---- per-wave partials to LDS (C/D layout: col=lane&15, row=quad*4+reg) ----
        {
            float* pw = part + wv * (BATS * PPAD);
            #pragma unroll
            for (int r = 0; r < 4; r++) {
                int m = quad * 4 + r;
                pw[m * PPAD + lm]      = acc0[r];
                pw[m * PPAD + 16 + lm] = acc1[r];
            }
        }
        __syncthreads();

        // ---- reduce 4 waves + tanh + store slice (512 outputs / 256 threads) ----
        for (int idx = tid; idx < BATS * ROWS; idx += 256) {
            int m = idx >> 5;
            int n = idx & 31;
            int o = m * PPAD + n;
            float s = part[o] + part[BATS * PPAD + o] + part[2 * BATS * PPAD + o]
                    + part[3 * BATS * PPAD + o];
            s = tanhf(s);
            if (t == T_ - 1) {
                out[(size_t)(b0 + m) * H_ + r0 + n] = s;       // final: fp32
            } else {
                hnext[(size_t)(b0 + m) * H_ + r0 + n] = (f16)s; // broadcast: fp16
            }
        }

        // ---- bg-segmented flag barrier (skip after last step) ----
        if (t < T_ - 1) {
            // make this WG's h stores visible at agent scope, then publish flag
            __builtin_amdgcn_fence(__ATOMIC_RELEASE, "agent");
            __syncthreads();   // all 4 waves' stores fenced before the flag goes up
            if (tid == 0) {
                __hip_atomic_store(&flags[wg], t + 1, __ATOMIC_RELEASE,
                                   __HIP_MEMORY_SCOPE_AGENT);
            }
            if (wv == 0) {
                // 64 lanes poll the 64 flags of this bg in one load per iteration
                const int* fbase = flags + (bg << 6);
                for (;;) {
                    int f = __hip_atomic_load(fbase + lane, __ATOMIC_RELAXED,
                                              __HIP_MEMORY_SCOPE_AGENT);
                    if (__all(f > t)) break;
                    __builtin_amdgcn_s_sleep(1);
                }
            }
            __syncthreads();   // waves 1-3 held here until wave 0 sees all flags
            __builtin_amdgcn_fence(__ATOMIC_ACQUIRE, "agent");
        }
    }
}

extern "C" void kernel_launch(void* const* d_in, const int* in_sizes, int n_in,
                              void* d_out, int out_size, void* d_ws, size_t ws_size,
                              hipStream_t stream)
{
    (void)in_sizes; (void)n_in; (void)out_size; (void)ws_size;
    const float* x    = (const float*)d_in[0];
    const float* Win  = (const float*)d_in[1];
    const float* Wres = (const float*)d_in[2];
    float* out = (float*)d_out;

    f16* h0 = (f16*)d_ws;
    f16* h1 = h0 + (size_t)B_ * H_;
    int* flags = (int*)((char*)d_ws + (size_t)2 * B_ * H_ * sizeof(f16));

    // zero h ping-pong buffers (h_0 = 0) and the flag array
    hipMemsetAsync(d_ws, 0,
                   (size_t)2 * B_ * H_ * sizeof(f16) + NWG * sizeof(int), stream);

    hipFuncSetAttribute((const void*)esn_kernel,
                        hipFuncAttributeMaxDynamicSharedMemorySize, LDS_TOTAL);

    void* args[] = {(void*)&x, (void*)&Win, (void*)&Wres, (void*)&out,
                    (void*)&h0, (void*)&h1, (void*)&flags};
    hipLaunchCooperativeKernel((const void*)esn_kernel, dim3(NWG), dim3(256),
                               args, LDS_TOTAL, stream);
}

// Round 3
// 3791.315 us; speedup vs baseline: 5.5671x; 3.2325x over previous
//
#include <hip/hip_runtime.h>

// ESN recurrence on MI355X: h_t = tanh(x_t @ W_in^T + h_{t-1} @ W_res^T)
// B=64, T=512, I=128, H=2048. Persistent cooperative kernel, 256 WGs (1/CU).
// WG (bg,j): batches [bg*16, bg*16+16), rows [j*32, j*32+32).
// W_res slice fp16 in LDS (resident all 512 steps); W_in slice fp16 hi+lo in LDS.
// R3: NO agent-scope fences (they emitted buffer_wbl2/buffer_inv = whole-L2
// flush/inv per WG per step — the 24 us/step cost). Instead h itself moves via
// relaxed agent-scope atomics (write-through stores, L2-bypassing loads), flags
// via relaxed agent atomics; __syncthreads' vmcnt(0) drain orders h before flag.

#define B_ 64
#define T_ 512
#define I_ 128
#define H_ 2048
#define NWG 256
#define ROWS 32          // output rows per WG
#define BATS 16          // batches per WG
#define WPAD 2056        // 2048 + 8 halves row pad
#define IPAD 136         // 128 + 8 halves row pad
#define PPAD 33          // partial row pad (break 32-bank stride)

typedef _Float16 f16;
typedef f16 f16x8 __attribute__((ext_vector_type(8)));
typedef float f32x4 __attribute__((ext_vector_type(4)));
typedef unsigned long long u64;

// LDS layout (bytes):
//   Wres  : ROWS*WPAD*2           = 131584
//   Win_hi: ROWS*IPAD*2           =   8704
//   Win_lo: ROWS*IPAD*2           =   8704
//   part  : 4*BATS*PPAD*4         =   8448
#define LDS_WRES   0
#define LDS_WINHI  131584
#define LDS_WINLO  (131584 + 8704)
#define LDS_PART   (131584 + 17408)
#define LDS_TOTAL  (131584 + 17408 + 8448)

extern "C" __global__ __launch_bounds__(256, 1)
void esn_kernel(const float* __restrict__ x, const float* __restrict__ Win,
                const float* __restrict__ Wres, float* __restrict__ out,
                f16* h0, f16* h1, int* flags)
{
    extern __shared__ char lds[];
    f16*   Wr   = (f16*)(lds + LDS_WRES);    // [ROWS][WPAD]
    f16*   Whi  = (f16*)(lds + LDS_WINHI);   // [ROWS][IPAD]
    f16*   Wlo  = (f16*)(lds + LDS_WINLO);   // [ROWS][IPAD]
    float* part = (float*)(lds + LDS_PART);  // [4][BATS][PPAD]

    const int tid  = threadIdx.x;
    const int wg   = blockIdx.x;
    const int j    = wg & 63;       // row group
    const int bg   = wg >> 6;       // batch group
    const int r0   = j * ROWS;
    const int b0   = bg * BATS;
    const int wv   = tid >> 6;      // wave 0..3
    const int lane = tid & 63;
    const int lm   = lane & 15;     // A: m index / B: n index / C: col index
    const int quad = lane >> 4;     // 0..3

    // ---- one-time init: stage W_res slice (fp32 -> fp16) into LDS ----
    for (int idx = tid; idx < ROWS * (H_ / 4); idx += 256) {
        int r  = idx >> 9;          // 512 float4 per row
        int c4 = idx & 511;
        const float4 v = ((const float4*)(Wres + (size_t)(r0 + r) * H_))[c4];
        f16* dst = Wr + r * WPAD + c4 * 4;
        dst[0] = (f16)v.x; dst[1] = (f16)v.y; dst[2] = (f16)v.z; dst[3] = (f16)v.w;
    }
    // ---- W_in slice as fp16 hi + lo (precision split) ----
    for (int idx = tid; idx < ROWS * (I_ / 4); idx += 256) {
        int r  = idx >> 5;          // 32 float4 per row
        int c4 = idx & 31;
        const float4 v = ((const float4*)(Win + (size_t)(r0 + r) * I_))[c4];
        float vv[4] = {v.x, v.y, v.z, v.w};
        f16* dh = Whi + r * IPAD + c4 * 4;
        f16* dl = Wlo + r * IPAD + c4 * 4;
        #pragma unroll
        for (int q = 0; q < 4; q++) {
            f16 hi = (f16)vv[q];
            dh[q] = hi;
            dl[q] = (f16)(vv[q] - (float)hi);
        }
    }
    __syncthreads();

    for (int t = 0; t < T_; t++) {
        const f16* hprev = (t & 1) ? h1 : h0;
        f16*       hnext = (t & 1) ? h0 : h1;

        f32x4 acc0 = {0.f, 0.f, 0.f, 0.f};
        f32x4 acc1 = {0.f, 0.f, 0.f, 0.f};

        // ---- prefetch h fragments via coherent (L2-bypassing) relaxed atomics ----
        // 16 x (2 x 8B) per lane; issued first so latency overlaps the x-part.
        f16x8 a[16];
        {
            const u64* hp = (const u64*)(hprev + (size_t)(b0 + lm) * H_ + wv * 512
                                         + quad * 8);
            #pragma unroll
            for (int ks = 0; ks < 16; ks++) {
                u64 u0 = __hip_atomic_load((const u64*)(hp + ks * 8), __ATOMIC_RELAXED,
                                           __HIP_MEMORY_SCOPE_AGENT);
                u64 u1 = __hip_atomic_load((const u64*)(hp + ks * 8 + 1), __ATOMIC_RELAXED,
                                           __HIP_MEMORY_SCOPE_AGENT);
                ((u64*)&a[ks])[0] = u0;
                ((u64*)&a[ks])[1] = u1;
            }
        }

        // ---- x_t @ W_in^T with fp16 hi/lo split; wave wv covers k in [wv*32, wv*32+32) ----
        {
            const int kin = wv * 32 + quad * 8;
            const float* xp = x + ((size_t)(b0 + lm) * T_ + t) * I_ + kin;
            float xf[8];
            *(float4*)(xf)     = *(const float4*)(xp);
            *(float4*)(xf + 4) = *(const float4*)(xp + 4);
            f16x8 xhi, xlo;
            #pragma unroll
            for (int q = 0; q < 8; q++) {
                f16 hi = (f16)xf[q];
                xhi[q] = hi;
                xlo[q] = (f16)(xf[q] - (float)hi);
            }
            f16x8 bh0 = *(const f16x8*)(Whi + lm * IPAD + kin);
            f16x8 bh1 = *(const f16x8*)(Whi + (lm + 16) * IPAD + kin);
            f16x8 bl0 = *(const f16x8*)(Wlo + lm * IPAD + kin);
            f16x8 bl1 = *(const f16x8*)(Wlo + (lm + 16) * IPAD + kin);
            acc0 = __builtin_amdgcn_mfma_f32_16x16x32_f16(xhi, bh0, acc0, 0, 0, 0);
            acc1 = __builtin_amdgcn_mfma_f32_16x16x32_f16(xhi, bh1, acc1, 0, 0, 0);
            acc0 = __builtin_amdgcn_mfma_f32_16x16x32_f16(xlo, bh0, acc0, 0, 0, 0);
            acc1 = __builtin_amdgcn_mfma_f32_16x16x32_f16(xlo, bh1, acc1, 0, 0, 0);
            acc0 = __builtin_amdgcn_mfma_f32_16x16x32_f16(xhi, bl0, acc0, 0, 0, 0);
            acc1 = __builtin_amdgcn_mfma_f32_16x16x32_f16(xhi, bl1, acc1, 0, 0, 0);
        }

        // ---- h_{t-1} @ W_res^T ; wave wv covers k in [wv*512, (wv+1)*512) ----
        {
            const f16* w0 = Wr + lm * WPAD + wv * 512 + quad * 8;
            const f16* w1 = Wr + (lm + 16) * WPAD + wv * 512 + quad * 8;
            #pragma unroll
            for (int ks = 0; ks < 16; ks++) {
                f16x8 bf0 = *(const f16x8*)(w0 + ks * 32);  // LDS ds_read_b128
                f16x8 bf1 = *(const f16x8*)(w1 + ks * 32);
                acc0 = __builtin_amdgcn_mfma_f32_16x16x32_f16(a[ks], bf0, acc0, 0, 0, 0);
                acc1 = __builtin_amdgcn_mfma_f32_16x16x32_f16(a[ks], bf1, acc1, 0, 0, 0);
            }
        }

        // ---- per-wave partials to LDS (C/D layout: col=lane&15, row=quad*4+reg) ----
        {
            float* pw = part + wv * (BATS * PPAD);
            #pragma unroll
            for (int r = 0; r < 4; r++) {
                int m = quad * 4 + r;
                pw[m * PPAD + lm]      = acc0[r];
                pw[m * PPAD + 16 + lm] = acc1[r];
            }
        }
        __syncthreads();

        // ---- reduce 4 waves + tanh + store; thread -> (m = tid>>4, n pair = tid&15) ----
        {
            const int m = tid >> 4;
            const int n = (tid & 15) * 2;
            const int o = m * PPAD + n;
            float s0 = part[o]     + part[BATS * PPAD + o]     + part[2 * BATS * PPAD + o]
                     + part[3 * BATS * PPAD + o];
            float s1 = part[o + 1] + part[BATS * PPAD + o + 1] + part[2 * BATS * PPAD + o + 1]
                     + part[3 * BATS * PPAD + o + 1];
            s0 = tanhf(s0);
            s1 = tanhf(s1);
            if (t == T_ - 1) {
                float* op = out + (size_t)(b0 + m) * H_ + r0 + n;
                op[0] = s0;
                op[1] = s1;
            } else {
                union { f16 h[2]; unsigned int u; } pk;
                pk.h[0] = (f16)s0;
                pk.h[1] = (f16)s1;
                // write-through to the coherence point (no L2 dirtying, no wbl2 needed)
                __hip_atomic_store((unsigned int*)(hnext + (size_t)(b0 + m) * H_ + r0 + n),
                                   pk.u, __ATOMIC_RELAXED, __HIP_MEMORY_SCOPE_AGENT);
            }
        }

        // ---- bg-segmented flag barrier, fence-free (skip after last step) ----
        if (t < T_ - 1) {
            // __syncthreads drains each wave's vmcnt(0): all h write-throughs have
            // reached the coherence point before any wave proceeds to the flag.
            __syncthreads();
            if (tid == 0) {
                __hip_atomic_store(&flags[wg], t + 1, __ATOMIC_RELAXED,
                                   __HIP_MEMORY_SCOPE_AGENT);
            }
            if (wv == 0) {
                // 64 lanes poll the 64 flags of this bg in one load per iteration
                const int* fbase = flags + (bg << 6);
                for (;;) {
                    int f = __hip_atomic_load(fbase + lane, __ATOMIC_RELAXED,
                                              __HIP_MEMORY_SCOPE_AGENT);
                    if (__all(f > t)) break;
                    __builtin_amdgcn_s_sleep(1);
                }
            }
            __syncthreads();   // waves 1-3 held here until wave 0 sees all flags
        }
    }
}

extern "C" void kernel_launch(void* const* d_in, const int* in_sizes, int n_in,
                              void* d_out, int out_size, void* d_ws, size_t ws_size,
                              hipStream_t stream)
{
    (void)in_sizes; (void)n_in; (void)out_size; (void)ws_size;
    const float* x    = (const float*)d_in[0];
    const float* Win  = (const float*)d_in[1];
    const float* Wres = (const float*)d_in[2];
    float* out = (float*)d_out;

    f16* h0 = (f16*)d_ws;
    f16* h1 = h0 + (size_t)B_ * H_;
    int* flags = (int*)((char*)d_ws + (size_t)2 * B_ * H_ * sizeof(f16));

    // zero h ping-pong buffers (h_0 = 0) and the flag array
    hipMemsetAsync(d_ws, 0,
                   (size_t)2 * B_ * H_ * sizeof(f16) + NWG * sizeof(int), stream);

    hipFuncSetAttribute((const void*)esn_kernel,
                        hipFuncAttributeMaxDynamicSharedMemorySize, LDS_TOTAL);

    void* args[] = {(void*)&x, (void*)&Win, (void*)&Wres, (void*)&out,
                    (void*)&h0, (void*)&h1, (void*)&flags};
    hipLaunchCooperativeKernel((const void*)esn_kernel, dim3(NWG), dim3(256),
                               args, LDS_TOTAL, stream);
}

// Round 6
// 3390.647 us; speedup vs baseline: 6.2250x; 1.1182x over previous
//
#include <hip/hip_runtime.h>

// ESN recurrence on MI355X: h_t = tanh(x_t @ W_in^T + h_{t-1} @ W_res^T)
// B=64, T=512, I=128, H=2048. Persistent cooperative kernel, 256 WGs (1/CU).
// WG (bg,j): batches [bg*16, bg*16+16), rows [j*32, j*32+32).
// W_res slice fp16 in LDS (resident); W_in slice fp16 hi+lo in LDS.
// R6: R5 + explicit s_waitcnt(0) before the publish barrier.
// Root cause of R4/R5 failures: __syncthreads does NOT reliably drain vmcnt
// for global stores (workgroup-scope ordering doesn't require it), so the tag
// store could issue while h stores/exchanges were still in flight. R3 only
// passed because its heavyweight barrier added slack. Fix: every wave executes
// s_waitcnt(0) after its h exchanges (response-based => committed at the
// coherence point) and BEFORE the barrier; tid0's tag store then provably
// follows all h commits. Tag visible => h visible.

#define B_ 64
#define T_ 512
#define I_ 128
#define H_ 2048
#define NWG 256
#define ROWS 32          // output rows per WG
#define BATS 16          // batches per WG
#define WPAD 2056        // 2048 + 8 halves row pad
#define IPAD 136         // 128 + 8 halves row pad
#define PPAD 33          // partial row pad (break 32-bank stride)
#define TSTRIDE 16       // tag stride in dwords (64 B -> one line per producer)

typedef _Float16 f16;
typedef f16 f16x8 __attribute__((ext_vector_type(8)));
typedef float f32x4 __attribute__((ext_vector_type(4)));
typedef unsigned long long u64;

// LDS layout (bytes):
//   Wres  : ROWS*WPAD*2           = 131584
//   Win_hi: ROWS*IPAD*2           =   8704
//   Win_lo: ROWS*IPAD*2           =   8704
//   part  : 4*BATS*PPAD*4         =   8448
#define LDS_WRES   0
#define LDS_WINHI  131584
#define LDS_WINLO  (131584 + 8704)
#define LDS_PART   (131584 + 17408)
#define LDS_TOTAL  (131584 + 17408 + 8448)

extern "C" __global__ __launch_bounds__(256, 1)
void esn_kernel(const float* __restrict__ x, const float* __restrict__ Win,
                const float* __restrict__ Wres, float* __restrict__ out,
                f16* h0, f16* h1, int* tags)
{
    extern __shared__ char lds[];
    f16*   Wr   = (f16*)(lds + LDS_WRES);    // [ROWS][WPAD]
    f16*   Whi  = (f16*)(lds + LDS_WINHI);   // [ROWS][IPAD]
    f16*   Wlo  = (f16*)(lds + LDS_WINLO);   // [ROWS][IPAD]
    float* part = (float*)(lds + LDS_PART);  // [4][BATS][PPAD]

    const int tid  = threadIdx.x;
    const int wg   = blockIdx.x;
    const int j    = wg & 63;       // row group
    const int bg   = wg >> 6;       // batch group
    const int r0   = j * ROWS;
    const int b0   = bg * BATS;
    const int wv   = tid >> 6;      // wave 0..3
    const int lane = tid & 63;
    const int lm   = lane & 15;     // A: m index / B: n index / C: col index
    const int quad = lane >> 4;     // 0..3

    // ---- one-time init: stage W_res slice (fp32 -> fp16) into LDS ----
    for (int idx = tid; idx < ROWS * (H_ / 4); idx += 256) {
        int r  = idx >> 9;          // 512 float4 per row
        int c4 = idx & 511;
        const float4 v = ((const float4*)(Wres + (size_t)(r0 + r) * H_))[c4];
        f16* dst = Wr + r * WPAD + c4 * 4;
        dst[0] = (f16)v.x; dst[1] = (f16)v.y; dst[2] = (f16)v.z; dst[3] = (f16)v.w;
    }
    // ---- W_in slice as fp16 hi + lo (precision split) ----
    for (int idx = tid; idx < ROWS * (I_ / 4); idx += 256) {
        int r  = idx >> 5;          // 32 float4 per row
        int c4 = idx & 31;
        const float4 v = ((const float4*)(Win + (size_t)(r0 + r) * I_))[c4];
        float vv[4] = {v.x, v.y, v.z, v.w};
        f16* dh = Whi + r * IPAD + c4 * 4;
        f16* dl = Wlo + r * IPAD + c4 * 4;
        #pragma unroll
        for (int q = 0; q < 4; q++) {
            f16 hi = (f16)vv[q];
            dh[q] = hi;
            dl[q] = (f16)(vv[q] - (float)hi);
        }
    }
    __syncthreads();

    for (int t = 0; t < T_; t++) {
        const f16* hprev = (t & 1) ? h1 : h0;
        f16*       hnext = (t & 1) ? h0 : h1;

        // ---- wait for my 16 producers: one vector poll, lane -> region ----
        // region r (=ks) of wave wv was produced by WG (bg, wv*16+r).
        // tag slot parity t&1 holds value t when fresh, t-2 when stale.
        {
            const int r = lane & 15;
            const int* tp = tags + (t & 1) * (NWG * TSTRIDE)
                          + ((bg << 6) + (wv << 4) + r) * TSTRIDE;
            for (;;) {
                int tg = __hip_atomic_load(tp, __ATOMIC_RELAXED,
                                           __HIP_MEMORY_SCOPE_AGENT);
                if (__all(tg >= t)) break;
                __builtin_amdgcn_s_sleep(1);
            }
            // compiler-only fence: keep the h loads below the poll
            asm volatile("" ::: "memory");
        }

        f32x4 acc0 = {0.f, 0.f, 0.f, 0.f};
        f32x4 acc1 = {0.f, 0.f, 0.f, 0.f};

        // ---- issue h fragment loads (coherent 8B relaxed atomics) ----
        f16x8 a[16];
        {
            const u64* hp = (const u64*)(hprev + (size_t)(b0 + lm) * H_ + wv * 512
                                         + quad * 8);
            #pragma unroll
            for (int ks = 0; ks < 16; ks++) {
                u64 u0 = __hip_atomic_load((const u64*)(hp + ks * 8), __ATOMIC_RELAXED,
                                           __HIP_MEMORY_SCOPE_AGENT);
                u64 u1 = __hip_atomic_load((const u64*)(hp + ks * 8 + 1), __ATOMIC_RELAXED,
                                           __HIP_MEMORY_SCOPE_AGENT);
                ((u64*)&a[ks])[0] = u0;
                ((u64*)&a[ks])[1] = u1;
            }
        }

        // ---- x_t @ W_in^T with fp16 hi/lo split (overlaps h-load latency) ----
        {
            const int kin = wv * 32 + quad * 8;
            const float* xp = x + ((size_t)(b0 + lm) * T_ + t) * I_ + kin;
            float xf[8];
            *(float4*)(xf)     = *(const float4*)(xp);
            *(float4*)(xf + 4) = *(const float4*)(xp + 4);
            f16x8 xhi, xlo;
            #pragma unroll
            for (int q = 0; q < 8; q++) {
                f16 hi = (f16)xf[q];
                xhi[q] = hi;
                xlo[q] = (f16)(xf[q] - (float)hi);
            }
            f16x8 bh0 = *(const f16x8*)(Whi + lm * IPAD + kin);
            f16x8 bh1 = *(const f16x8*)(Whi + (lm + 16) * IPAD + kin);
            f16x8 bl0 = *(const f16x8*)(Wlo + lm * IPAD + kin);
            f16x8 bl1 = *(const f16x8*)(Wlo + (lm + 16) * IPAD + kin);
            acc0 = __builtin_amdgcn_mfma_f32_16x16x32_f16(xhi, bh0, acc0, 0, 0, 0);
            acc1 = __builtin_amdgcn_mfma_f32_16x16x32_f16(xhi, bh1, acc1, 0, 0, 0);
            acc0 = __builtin_amdgcn_mfma_f32_16x16x32_f16(xlo, bh0, acc0, 0, 0, 0);
            acc1 = __builtin_amdgcn_mfma_f32_16x16x32_f16(xlo, bh1, acc1, 0, 0, 0);
            acc0 = __builtin_amdgcn_mfma_f32_16x16x32_f16(xhi, bl0, acc0, 0, 0, 0);
            acc1 = __builtin_amdgcn_mfma_f32_16x16x32_f16(xhi, bl1, acc1, 0, 0, 0);
        }

        // ---- h_{t-1} @ W_res^T ; wave wv covers k in [wv*512, (wv+1)*512) ----
        {
            const f16* w0 = Wr + lm * WPAD + wv * 512 + quad * 8;
            const f16* w1 = Wr + (lm + 16) * WPAD + wv * 512 + quad * 8;
            #pragma unroll
            for (int ks = 0; ks < 16; ks++) {
                f16x8 bf0 = *(const f16x8*)(w0 + ks * 32);  // LDS ds_read_b128
                f16x8 bf1 = *(const f16x8*)(w1 + ks * 32);
                acc0 = __builtin_amdgcn_mfma_f32_16x16x32_f16(a[ks], bf0, acc0, 0, 0, 0);
                acc1 = __builtin_amdgcn_mfma_f32_16x16x32_f16(a[ks], bf1, acc1, 0, 0, 0);
            }
        }

        // ---- per-wave partials to LDS (C/D layout: col=lane&15, row=quad*4+reg) ----
        {
            float* pw = part + wv * (BATS * PPAD);
            #pragma unroll
            for (int r = 0; r < 4; r++) {
                int m = quad * 4 + r;
                pw[m * PPAD + lm]      = acc0[r];
                pw[m * PPAD + 16 + lm] = acc1[r];
            }
        }
        __syncthreads();

        // ---- reduce 4 waves + tanh + store; thread -> (m = tid>>4, n pair = tid&15) ----
        {
            const int m = tid >> 4;
            const int n = (tid & 15) * 2;
            const int o = m * PPAD + n;
            float s0 = part[o]     + part[BATS * PPAD + o]     + part[2 * BATS * PPAD + o]
                     + part[3 * BATS * PPAD + o];
            float s1 = part[o + 1] + part[BATS * PPAD + o + 1] + part[2 * BATS * PPAD + o + 1]
                     + part[3 * BATS * PPAD + o + 1];
            s0 = tanhf(s0);
            s1 = tanhf(s1);
            if (t == T_ - 1) {
                float* op = out + (size_t)(b0 + m) * H_ + r0 + n;
                op[0] = s0;
                op[1] = s1;
            } else {
                union { f16 h[2]; unsigned int u; } pk;
                pk.h[0] = (f16)s0;
                pk.h[1] = (f16)s1;
                // atomic EXCHANGE (result discarded): vmcnt acks only when the
                // response returns from the coherence point.
                (void)__hip_atomic_exchange(
                    (unsigned int*)(hnext + (size_t)(b0 + m) * H_ + r0 + n),
                    pk.u, __ATOMIC_RELAXED, __HIP_MEMORY_SCOPE_AGENT);
            }
        }

        // ---- publish tag: FORCE vmcnt(0) drain (the missing piece in R4/R5:
        // __syncthreads alone does not drain global-store vmcnt), then barrier,
        // then one tag store — provably after all h commits.  ----
        if (t < T_ - 1) {
            __builtin_amdgcn_s_waitcnt(0);   // vmcnt(0) lgkmcnt(0) expcnt(0), per wave
            __syncthreads();                 // all waves drained before tag goes up
            if (tid == 0) {
                __hip_atomic_store(tags + ((t + 1) & 1) * (NWG * TSTRIDE) + wg * TSTRIDE,
                                   t + 1, __ATOMIC_RELAXED, __HIP_MEMORY_SCOPE_AGENT);
            }
            // no second barrier, no acquire fence: next-step pollers gate progress
        }
    }
}

extern "C" void kernel_launch(void* const* d_in, const int* in_sizes, int n_in,
                              void* d_out, int out_size, void* d_ws, size_t ws_size,
                              hipStream_t stream)
{
    (void)in_sizes; (void)n_in; (void)out_size; (void)ws_size;
    const float* x    = (const float*)d_in[0];
    const float* Win  = (const float*)d_in[1];
    const float* Wres = (const float*)d_in[2];
    float* out = (float*)d_out;

    f16* h0 = (f16*)d_ws;
    f16* h1 = h0 + (size_t)B_ * H_;
    int* tags = (int*)((char*)d_ws + (size_t)2 * B_ * H_ * sizeof(f16));

    // zero h ping-pong buffers (h_0 = 0) and both tag parities
    // (tag init 0 => step 0 pollers pass immediately: 0 >= 0)
    hipMemsetAsync(d_ws, 0,
                   (size_t)2 * B_ * H_ * sizeof(f16)
                   + (size_t)2 * NWG * TSTRIDE * sizeof(int), stream);

    hipFuncSetAttribute((const void*)esn_kernel,
                        hipFuncAttributeMaxDynamicSharedMemorySize, LDS_TOTAL);

    void* args[] = {(void*)&x, (void*)&Win, (void*)&Wres, (void*)&out,
                    (void*)&h0, (void*)&h1, (void*)&tags};
    hipLaunchCooperativeKernel((const void*)esn_kernel, dim3(NWG), dim3(256),
                               args, LDS_TOTAL, stream);
}